// Round 10
// baseline (197.779 us; speedup 1.0000x reference)
//
#include <hip/hip_runtime.h>

// Problem constants (B,T,C,H,Dh) = (4,2048,1024,16,64); M = B*T = 8192.
#define SEQ_T 2048
#define NBATCH 4
#define CDIM 1024
#define NHEAD 16
#define MROWS 8192      // NBATCH * SEQ_T
#define QKVC 3072       // 3*CDIM

typedef unsigned short u16;
typedef __bf16 bf16x8 __attribute__((ext_vector_type(8)));
typedef float f32x4 __attribute__((ext_vector_type(4)));
typedef unsigned uint32x4 __attribute__((ext_vector_type(4)));

__device__ __forceinline__ u16 f32_to_bf16(float f) {
  union { float f; unsigned int u; } v; v.f = f;
  unsigned int u = v.u;
  unsigned int r = ((u >> 16) & 1u) + 0x7fffu;   // round-to-nearest-even
  return (u16)((u + r) >> 16);
}

__device__ __forceinline__ void gload_lds16(const u16* g, u16* l) {
  __builtin_amdgcn_global_load_lds(
      (const __attribute__((address_space(1))) void*)g,
      (__attribute__((address_space(3))) void*)l, 16, 0, 0);
}

// ---------------------------------------------------------------- cast f32 -> bf16
__global__ __launch_bounds__(256) void cast_bf16_kernel(const float* __restrict__ in,
                                                        u16* __restrict__ out, int n4) {
  int i = blockIdx.x * 256 + threadIdx.x;
  if (i >= n4) return;
  float4 v = ((const float4*)in)[i];
  ushort4 o;
  o.x = f32_to_bf16(v.x); o.y = f32_to_bf16(v.y);
  o.z = f32_to_bf16(v.z); o.w = f32_to_bf16(v.w);
  ((ushort4*)out)[i] = o;
}

// ------------------------------------------- transpose + cast: out[c][r] = in[r][c]
__global__ void transpose_cast_kernel(const float* __restrict__ in, u16* __restrict__ out,
                                      int R, int Cc) {
  __shared__ float tile[32][33];
  int c0 = blockIdx.x * 32, r0 = blockIdx.y * 32;
  int tx = threadIdx.x, ty = threadIdx.y;   // 32 x 8
  #pragma unroll
  for (int i = 0; i < 32; i += 8)
    tile[ty + i][tx] = in[(size_t)(r0 + ty + i) * Cc + c0 + tx];
  __syncthreads();
  #pragma unroll
  for (int i = 0; i < 32; i += 8)
    out[(size_t)(c0 + ty + i) * R + r0 + tx] = f32_to_bf16(tile[tx][ty + i]);
}

// ---------------------------------------------------------------- K repack
// Lane-linear fragment tiles: per (bh, 32-kv chunk): 4 frags (t,i), each 64
// lanes x 16B; lane l holds K[kv0 + t*16 + (l&15)][i*32 + (l>>4)*8 .. +8].
__global__ __launch_bounds__(256) void repack_k_kernel(const u16* __restrict__ QKV,
                                                       u16* __restrict__ Kc) {
  const int kvt32 = blockIdx.x, bh = blockIdx.y;
  const int b = bh >> 4, h = bh & 15;
  const int tid = threadIdx.x;
  const int f = tid >> 6, l = tid & 63;
  const int t = f >> 1, i = f & 1;
  const int row = kvt32 * 32 + t * 16 + (l & 15);
  const bf16x8 v = *(const bf16x8*)(QKV + (size_t)b * SEQ_T * QKVC + (size_t)row * QKVC +
                                    CDIM + h * 64 + i * 32 + (l >> 4) * 8);
  *(bf16x8*)(Kc + (size_t)bh * 131072 + (size_t)kvt32 * 2048 + f * 512 + l * 8) = v;
}

// ---------------------------------------------------------------- V repack
// Lane-linear: per (bh, 32-kv chunk): 4 d-frags; lane l = (lhi=l>>4, l15=l&15)
// holds V[kv0 + lhi*8 + j][d*16 + l15], at frag*1KB + lane*16B.
__global__ void repack_v_kernel(const u16* __restrict__ QKV, u16* __restrict__ Vc) {
  __shared__ u16 tile[32][34];
  const int t0 = blockIdx.x * 32, d0 = blockIdx.y * 32;
  const int bh = blockIdx.z;
  const int b = bh >> 4, h = bh & 15;
  const int tx = threadIdx.x, ty = threadIdx.y;   // 32 x 8
  const u16* Vp = QKV + (size_t)b * SEQ_T * QKVC + 2 * CDIM + h * 64 + d0;
  #pragma unroll
  for (int i = 0; i < 32; i += 8)
    tile[ty + i][tx] = Vp[(size_t)(t0 + ty + i) * QKVC + tx];
  __syncthreads();
  const int tid = ty * 32 + tx;
  if (tid < 128) {
    const int bc = tid >> 2, ag = tid & 3;        // bc: d-col 0..31, ag: kv-octet 0..3
    union { u16 u[8]; bf16x8 v; } o;
    #pragma unroll
    for (int j = 0; j < 8; ++j) o.u[j] = tile[ag * 8 + j][bc];
    const int dvl = d0 + bc;
    *(bf16x8*)(Vc + (size_t)bh * 131072 + (size_t)(t0 >> 5) * 2048 +
               (dvl >> 4) * 512 + ag * 128 + (dvl & 15) * 8) = o.v;
  }
}

// ---------------------------------------------------------------- bf16 MFMA GEMM
// Round-9 pipelined 128x128 GEMM, BK=32, K=1024 (NKT=32): triple-buffered LDS,
// counted vmcnt(4) + raw barrier, chunk-rotation swizzle, setprio MFMA cluster.
template <typename OT, bool QSCALE>
__global__ __launch_bounds__(256, 3)
void gemm_bt_kernel(const u16* __restrict__ A, const u16* __restrict__ Bt,
                    OT* __restrict__ C, int N, int K) {
  __shared__ u16 sA[3][4096];
  __shared__ u16 sB[3][4096];
  const int tid = threadIdx.x;
  const int lane = tid & 63, w = tid >> 6;
  const int wm = w >> 1, wn = w & 1;
  const int l15 = lane & 15, lhi = lane >> 4;
  const int row0 = blockIdx.x * 128, col0 = blockIdx.y * 128;

  const int oln  = ((lane & 3) - (lane >> 2)) & 3;
  const int srow = w * 32 + (lane >> 2);
  const u16* aS = A  + (size_t)(row0 + srow) * K + oln * 8;
  const u16* bS = Bt + (size_t)(col0 + srow) * K + oln * 8;
  const int stD = w * 1024;
  const int rdA = (wm * 64 + l15) * 32 + ((lhi + l15) & 3) * 8;
  const int rdB = (wn * 64 + l15) * 32 + ((lhi + l15) & 3) * 8;

  f32x4 acc[4][4] = {};

#define STAGE(KT, S)                                                            \
  {                                                                             \
    const size_t ko = (size_t)(KT) * 32;                                        \
    gload_lds16(aS + ko,          &sA[S][stD]);                                 \
    gload_lds16(aS + ko + 16 * K, &sA[S][stD + 512]);                           \
    gload_lds16(bS + ko,          &sB[S][stD]);                                 \
    gload_lds16(bS + ko + 16 * K, &sB[S][stD + 512]);                           \
  }
#define COMPUTE(S)                                                              \
  {                                                                             \
    bf16x8 af[4], bf[4];                                                        \
    _Pragma("unroll") for (int mi = 0; mi < 4; ++mi)                            \
      af[mi] = *(const bf16x8*)&sA[S][rdA + mi * 512];                          \
    _Pragma("unroll") for (int ni = 0; ni < 4; ++ni)                            \
      bf[ni] = *(const bf16x8*)&sB[S][rdB + ni * 512];                          \
    __builtin_amdgcn_s_setprio(1);                                              \
    _Pragma("unroll") for (int mi = 0; mi < 4; ++mi)                            \
      _Pragma("unroll") for (int ni = 0; ni < 4; ++ni)                          \
        acc[mi][ni] = __builtin_amdgcn_mfma_f32_16x16x32_bf16(af[mi], bf[ni],   \
                                                              acc[mi][ni], 0, 0, 0); \
    __builtin_amdgcn_s_setprio(0);                                              \
  }
#define WAITBAR4                                                                \
  asm volatile("s_waitcnt vmcnt(4)" ::: "memory");                              \
  __builtin_amdgcn_sched_barrier(0);                                            \
  __builtin_amdgcn_s_barrier();

  STAGE(0, 0);
  STAGE(1, 1);
  WAITBAR4;

  #pragma unroll 1
  for (int kt = 0; kt < 30; kt += 3) {
    STAGE(kt + 2, 2); COMPUTE(0); WAITBAR4;
    STAGE(kt + 3, 0); COMPUTE(1); WAITBAR4;
    STAGE(kt + 4, 1); COMPUTE(2); WAITBAR4;
  }
  COMPUTE(0);
  asm volatile("s_waitcnt vmcnt(0)" ::: "memory");
  __builtin_amdgcn_sched_barrier(0);
  __builtin_amdgcn_s_barrier();
  COMPUTE(1);
#undef STAGE
#undef COMPUTE
#undef WAITBAR4

  #pragma unroll
  for (int mt = 0; mt < 4; ++mt)
    #pragma unroll
    for (int nt = 0; nt < 4; ++nt)
      #pragma unroll
      for (int r = 0; r < 4; ++r) {
        const int rr = row0 + wm * 64 + mt * 16 + lhi * 4 + r;
        const int cc = col0 + wn * 64 + nt * 16 + l15;
        float v = acc[mt][nt][r];
        if (QSCALE && cc < CDIM) v *= 0.18033688011f;   // 0.125 * log2(e)
        if constexpr (sizeof(OT) == 2) C[(size_t)rr * N + cc] = f32_to_bf16(v);
        else                           C[(size_t)rr * N + cc] = v;
      }
}

// ---------------------------------------------------------------- flash attention
// Round-10: uniform block duration.  Wave w of block k takes pair k + 16*w
// (was 4k + w), so the block's iteration count ncmax = (127-k)/2+1 varies only
// 57..64 across blocks (was 34..64) -> no end-of-kernel residency tail.
// Waves whose jobs finish early still stage+barrier (guards unchanged).
template <bool DOMASK>
__device__ __forceinline__ void attn_step(const bf16x8 (&qf)[2],
                                          const bf16x8 (&kf)[2][2],
                                          const bf16x8 (&vb)[4],
                                          f32x4 (&acc)[4], float& lsum,
                                          int l15, int lhi, int kv0, int qg) {
  f32x4 st[2];
  #pragma unroll
  for (int t = 0; t < 2; ++t) {
    f32x4 z = {0.f, 0.f, 0.f, 0.f};
    z = __builtin_amdgcn_mfma_f32_16x16x32_bf16(kf[t][0], qf[0], z, 0, 0, 0);
    z = __builtin_amdgcn_mfma_f32_16x16x32_bf16(kf[t][1], qf[1], z, 0, 0, 0);
    st[t] = z;
  }
  #pragma unroll
  for (int t = 0; t < 2; ++t)
    #pragma unroll
    for (int r = 0; r < 4; ++r) {
      float sv = st[t][r];                       // Q pre-scaled: log2-domain score
      if (DOMASK) {
        const int kvg = kv0 + t * 16 + lhi * 4 + r;
        sv = (kvg > qg) ? -__builtin_inff() : sv;
      }
      const float p = exp2f(sv);
      st[t][r] = p;
      lsum += p;
    }
  // In-register P^T -> PA transpose among the 4 lane-groups sharing l15.
  unsigned c00, c01, c10, c11;
  asm("v_cvt_pk_bf16_f32 %0, %1, %2" : "=v"(c00) : "v"(st[0][0]), "v"(st[0][1]));
  asm("v_cvt_pk_bf16_f32 %0, %1, %2" : "=v"(c01) : "v"(st[0][2]), "v"(st[0][3]));
  asm("v_cvt_pk_bf16_f32 %0, %1, %2" : "=v"(c10) : "v"(st[1][0]), "v"(st[1][1]));
  asm("v_cvt_pk_bf16_f32 %0, %1, %2" : "=v"(c11) : "v"(st[1][2]), "v"(st[1][3]));
  asm("v_permlane32_swap_b32 %0, %1" : "+v"(c00), "+v"(c10));
  asm("v_permlane32_swap_b32 %0, %1" : "+v"(c01), "+v"(c11));
  asm("v_permlane16_swap_b32 %0, %1" : "+v"(c00), "+v"(c10));
  asm("v_permlane16_swap_b32 %0, %1" : "+v"(c01), "+v"(c11));
  uint32x4 pw; pw[0] = c00; pw[1] = c01; pw[2] = c10; pw[3] = c11;
  const bf16x8 pa = __builtin_bit_cast(bf16x8, pw);
  #pragma unroll
  for (int d = 0; d < 4; ++d)
    acc[d] = __builtin_amdgcn_mfma_f32_16x16x32_bf16(pa, vb[d], acc[d], 0, 0, 0);
}

__global__ __launch_bounds__(256, 4) void attn_kernel(const u16* __restrict__ QKV,
                                                      const u16* __restrict__ Kc,
                                                      const u16* __restrict__ Vc,
                                                      u16* __restrict__ Y) {
  __shared__ u16 Kl[2][2048];     // [buf][4 frags x 64 lanes x 8 u16] = 4KB each
  __shared__ u16 Vl[2][2048];
  const int tid = threadIdx.x, lane = tid & 63, wid = tid >> 6;
  const int l15 = lane & 15, lhi = lane >> 4;
  // XCD-aware decode: id = xcd + 8*k + 128*(bh>>3), xcd = bh&7.
  const int id = blockIdx.x;
  const int xcd = id & 7, k = (id >> 3) & 15, hi3 = id >> 7;
  const int bh = hi3 * 8 + xcd;
  const int b = bh >> 4, h = bh & 15;
  const int pa = k + 16 * wid;                   // interleaved pair index 0..63
  const int qA0 = pa * 16, qB0 = (127 - pa) * 16;
  const int nchA = pa / 2 + 1, nchB = (127 - pa) / 2 + 1;
  const int ncmax = (127 - k) / 2 + 1;           // block-uniform chunk count (wid 0)
  const size_t base = (size_t)b * SEQ_T * QKVC;
  const u16* Qp  = QKV + base + h * 64;
  const u16* KcC = Kc + (size_t)bh * 131072;
  const u16* VcC = Vc + (size_t)bh * 131072;

  // stage chunk 0 (each wave: 1KB of K + 1KB of V)
  gload_lds16(KcC + wid * 512 + lane * 8, &Kl[0][wid * 512]);
  gload_lds16(VcC + wid * 512 + lane * 8, &Vl[0][wid * 512]);

  bf16x8 qfA[2], qfB[2];
  #pragma unroll
  for (int i = 0; i < 2; ++i) {
    qfA[i] = *(const bf16x8*)(Qp + (size_t)(qA0 + l15) * QKVC + i * 32 + lhi * 8);
    qfB[i] = *(const bf16x8*)(Qp + (size_t)(qB0 + l15) * QKVC + i * 32 + lhi * 8);
  }
  const int qgA = qA0 + l15, qgB = qB0 + l15;

  f32x4 accA[4] = {}, accB[4] = {};
  float lsA = 0.f, lsB = 0.f;

  __syncthreads();

  int cbuf = 0;
  for (int ic = 0; ic < ncmax; ++ic) {
    // prefetch next chunk into the other buffer (block-uniform condition)
    if (ic + 1 < ncmax) {
      const u16* kg = KcC + (size_t)(ic + 1) * 2048 + wid * 512 + lane * 8;
      const u16* vg = VcC + (size_t)(ic + 1) * 2048 + wid * 512 + lane * 8;
      gload_lds16(kg, &Kl[cbuf ^ 1][wid * 512]);
      gload_lds16(vg, &Vl[cbuf ^ 1][wid * 512]);
    }
    // conflict-free lane-linear ds_read_b128 fragments (shared by both jobs)
    const u16* kb = &Kl[cbuf][0];
    const u16* vp = &Vl[cbuf][0];
    bf16x8 kf[2][2], vb[4];
    #pragma unroll
    for (int t = 0; t < 2; ++t)
      #pragma unroll
      for (int i = 0; i < 2; ++i)
        kf[t][i] = *(const bf16x8*)(kb + (t * 2 + i) * 512 + lane * 8);
    #pragma unroll
    for (int d = 0; d < 4; ++d)
      vb[d] = *(const bf16x8*)(vp + d * 512 + lane * 8);

    const int kv0 = ic * 32;
    if (ic < nchB) {
      if (ic == nchB - 1)
        attn_step<true>(qfB, kf, vb, accB, lsB, l15, lhi, kv0, qgB);
      else
        attn_step<false>(qfB, kf, vb, accB, lsB, l15, lhi, kv0, qgB);
    }
    if (ic < nchA) {
      if (ic == nchA - 1)
        attn_step<true>(qfA, kf, vb, accA, lsA, l15, lhi, kv0, qgA);
      else
        attn_step<false>(qfA, kf, vb, accA, lsA, l15, lhi, kv0, qgA);
    }
    __syncthreads();
    cbuf ^= 1;
  }

  // epilogue: reduce per-lane partial row-sums, divide, store
  lsA += __shfl_xor(lsA, 16); lsA += __shfl_xor(lsA, 32);
  lsB += __shfl_xor(lsB, 16); lsB += __shfl_xor(lsB, 32);

  u16* Yp = Y + (size_t)b * SEQ_T * CDIM + h * 64;
  #pragma unroll
  for (int r = 0; r < 4; ++r) {
    const float lrA = __shfl(lsA, lhi * 4 + r, 64);
    const float lrB = __shfl(lsB, lhi * 4 + r, 64);
    const float ivA = 1.0f / lrA, ivB = 1.0f / lrB;
    #pragma unroll
    for (int d = 0; d < 4; ++d) {
      Yp[(size_t)(qA0 + lhi * 4 + r) * CDIM + d * 16 + l15] = f32_to_bf16(accA[d][r] * ivA);
      Yp[(size_t)(qB0 + lhi * 4 + r) * CDIM + d * 16 + l15] = f32_to_bf16(accB[d][r] * ivB);
    }
  }
}

// ---------------------------------------------------------------- launch
extern "C" void kernel_launch(void* const* d_in, const int* in_sizes, int n_in,
                              void* d_out, int out_size, void* d_ws, size_t ws_size,
                              hipStream_t stream) {
  const float* x      = (const float*)d_in[0];
  const float* w_qkv  = (const float*)d_in[1];
  const float* w_proj = (const float*)d_in[2];
  float* out = (float*)d_out;

  u16* Xb  = (u16*)d_ws;                                // 8192*1024 bf16 (dead after GEMM1)
  u16* Wqt = Xb  + (size_t)MROWS * CDIM;                // 3072*1024
  u16* Wpt = Wqt + (size_t)QKVC * CDIM;                 // 1024*1024
  u16* QKV = Wpt + (size_t)CDIM * CDIM;                 // 8192*3072
  u16* Yb  = QKV + (size_t)MROWS * QKVC;                // 8192*1024
  u16* Vc  = Yb  + (size_t)MROWS * CDIM;                // 64*131072 (blocked V)
  u16* Kc  = Xb;                                        // 64*131072 (blocked K, aliases Xb)

  // casts / transposes
  cast_bf16_kernel<<<(MROWS * CDIM / 4 + 255) / 256, 256, 0, stream>>>(x, Xb, MROWS * CDIM / 4);
  transpose_cast_kernel<<<dim3(QKVC / 32, CDIM / 32), dim3(32, 8), 0, stream>>>(w_qkv, Wqt, CDIM, QKVC);
  transpose_cast_kernel<<<dim3(CDIM / 32, CDIM / 32), dim3(32, 8), 0, stream>>>(w_proj, Wpt, CDIM, CDIM);

  // qkv = x @ w_qkv  (bf16 out; Q columns pre-scaled by 0.125*log2e)
  gemm_bt_kernel<u16, true><<<dim3(MROWS / 128, QKVC / 128), 256, 0, stream>>>(Xb, Wqt, QKV, QKVC, CDIM);

  // K/V repack into lane-linear fragment tiles (Kc overwrites Xb - safe after GEMM1)
  repack_k_kernel<<<dim3(SEQ_T / 32, NBATCH * NHEAD), 256, 0, stream>>>(QKV, Kc);
  repack_v_kernel<<<dim3(SEQ_T / 32, 2, NBATCH * NHEAD), dim3(32, 8), 0, stream>>>(QKV, Vc);

  // attention (interleaved balanced pairs -> uniform block duration, XCD-clustered)
  attn_kernel<<<1024, 256, 0, stream>>>(QKV, Kc, Vc, Yb);

  // out = y @ w_proj  (f32 out)
  gemm_bt_kernel<float, false><<<dim3(MROWS / 128, CDIM / 128), 256, 0, stream>>>(Yb, Wpt, out, CDIM, CDIM);
}

// Round 11
// 189.028 us; speedup vs baseline: 1.0463x; 1.0463x over previous
//
#include <hip/hip_runtime.h>

// Problem constants (B,T,C,H,Dh) = (4,2048,1024,16,64); M = B*T = 8192.
#define SEQ_T 2048
#define NBATCH 4
#define CDIM 1024
#define NHEAD 16
#define MROWS 8192      // NBATCH * SEQ_T
#define QKVC 3072       // 3*CDIM

typedef unsigned short u16;
typedef __bf16 bf16x8 __attribute__((ext_vector_type(8)));
typedef float f32x4 __attribute__((ext_vector_type(4)));
typedef unsigned short u16x8 __attribute__((ext_vector_type(8)));
typedef unsigned uint32x4 __attribute__((ext_vector_type(4)));

__device__ __forceinline__ u16 f32_to_bf16(float f) {
  union { float f; unsigned int u; } v; v.f = f;
  unsigned int u = v.u;
  unsigned int r = ((u >> 16) & 1u) + 0x7fffu;   // round-to-nearest-even
  return (u16)((u + r) >> 16);
}

__device__ __forceinline__ void gload_lds16(const u16* g, u16* l) {
  __builtin_amdgcn_global_load_lds(
      (const __attribute__((address_space(1))) void*)g,
      (__attribute__((address_space(3))) void*)l, 16, 0, 0);
}

// ---------------------------------------------------------------- cast f32 -> bf16
__global__ __launch_bounds__(256) void cast_bf16_kernel(const float* __restrict__ in,
                                                        u16* __restrict__ out, int n4) {
  int i = blockIdx.x * 256 + threadIdx.x;
  if (i >= n4) return;
  float4 v = ((const float4*)in)[i];
  ushort4 o;
  o.x = f32_to_bf16(v.x); o.y = f32_to_bf16(v.y);
  o.z = f32_to_bf16(v.z); o.w = f32_to_bf16(v.w);
  ((ushort4*)out)[i] = o;
}

// ------------------------------------------- transpose + cast: out[c][r] = in[r][c]
__global__ void transpose_cast_kernel(const float* __restrict__ in, u16* __restrict__ out,
                                      int R, int Cc) {
  __shared__ float tile[32][33];
  int c0 = blockIdx.x * 32, r0 = blockIdx.y * 32;
  int tx = threadIdx.x, ty = threadIdx.y;   // 32 x 8
  #pragma unroll
  for (int i = 0; i < 32; i += 8)
    tile[ty + i][tx] = in[(size_t)(r0 + ty + i) * Cc + c0 + tx];
  __syncthreads();
  #pragma unroll
  for (int i = 0; i < 32; i += 8)
    out[(size_t)(c0 + ty + i) * R + r0 + tx] = f32_to_bf16(tile[tx][ty + i]);
}

// ---------------------------------------------------------------- K repack
// Lane-linear fragment tiles: per (bh, 32-kv chunk): 4 frags (t,i), each 64
// lanes x 16B; lane l holds K[kv0 + t*16 + (l&15)][i*32 + (l>>4)*8 .. +8].
__global__ __launch_bounds__(256) void repack_k_kernel(const u16* __restrict__ QKV,
                                                       u16* __restrict__ Kc) {
  const int kvt32 = blockIdx.x, bh = blockIdx.y;
  const int b = bh >> 4, h = bh & 15;
  const int tid = threadIdx.x;
  const int f = tid >> 6, l = tid & 63;
  const int t = f >> 1, i = f & 1;
  const int row = kvt32 * 32 + t * 16 + (l & 15);
  const bf16x8 v = *(const bf16x8*)(QKV + (size_t)b * SEQ_T * QKVC + (size_t)row * QKVC +
                                    CDIM + h * 64 + i * 32 + (l >> 4) * 8);
  *(bf16x8*)(Kc + (size_t)bh * 131072 + (size_t)kvt32 * 2048 + f * 512 + l * 8) = v;
}

// ---------------------------------------------------------------- V repack
// Lane-linear: per (bh, 32-kv chunk): 4 d-frags; lane l = (lhi=l>>4, l15=l&15)
// holds V[kv0 + lhi*8 + j][d*16 + l15], at frag*1KB + lane*16B.
__global__ void repack_v_kernel(const u16* __restrict__ QKV, u16* __restrict__ Vc) {
  __shared__ u16 tile[32][34];
  const int t0 = blockIdx.x * 32, d0 = blockIdx.y * 32;
  const int bh = blockIdx.z;
  const int b = bh >> 4, h = bh & 15;
  const int tx = threadIdx.x, ty = threadIdx.y;   // 32 x 8
  const u16* Vp = QKV + (size_t)b * SEQ_T * QKVC + 2 * CDIM + h * 64 + d0;
  #pragma unroll
  for (int i = 0; i < 32; i += 8)
    tile[ty + i][tx] = Vp[(size_t)(t0 + ty + i) * QKVC + tx];
  __syncthreads();
  const int tid = ty * 32 + tx;
  if (tid < 128) {
    const int bc = tid >> 2, ag = tid & 3;        // bc: d-col 0..31, ag: kv-octet 0..3
    union { u16 u[8]; bf16x8 v; } o;
    #pragma unroll
    for (int j = 0; j < 8; ++j) o.u[j] = tile[ag * 8 + j][bc];
    const int dvl = d0 + bc;
    *(bf16x8*)(Vc + (size_t)bh * 131072 + (size_t)(t0 >> 5) * 2048 +
               (dvl >> 4) * 512 + ag * 128 + (dvl & 15) * 8) = o.v;
  }
}

// ---------------------------------------------------------------- bf16 MFMA GEMM
// Round-9 pipelined 128x128 GEMM, BK=32, K=1024 (NKT=32): triple-buffered LDS,
// counted vmcnt(4) + raw barrier, chunk-rotation swizzle, setprio MFMA cluster.
template <typename OT, bool QSCALE>
__global__ __launch_bounds__(256, 3)
void gemm_bt_kernel(const u16* __restrict__ A, const u16* __restrict__ Bt,
                    OT* __restrict__ C, int N, int K) {
  __shared__ u16 sA[3][4096];
  __shared__ u16 sB[3][4096];
  const int tid = threadIdx.x;
  const int lane = tid & 63, w = tid >> 6;
  const int wm = w >> 1, wn = w & 1;
  const int l15 = lane & 15, lhi = lane >> 4;
  const int row0 = blockIdx.x * 128, col0 = blockIdx.y * 128;

  const int oln  = ((lane & 3) - (lane >> 2)) & 3;
  const int srow = w * 32 + (lane >> 2);
  const u16* aS = A  + (size_t)(row0 + srow) * K + oln * 8;
  const u16* bS = Bt + (size_t)(col0 + srow) * K + oln * 8;
  const int stD = w * 1024;
  const int rdA = (wm * 64 + l15) * 32 + ((lhi + l15) & 3) * 8;
  const int rdB = (wn * 64 + l15) * 32 + ((lhi + l15) & 3) * 8;

  f32x4 acc[4][4] = {};

#define STAGE(KT, S)                                                            \
  {                                                                             \
    const size_t ko = (size_t)(KT) * 32;                                        \
    gload_lds16(aS + ko,          &sA[S][stD]);                                 \
    gload_lds16(aS + ko + 16 * K, &sA[S][stD + 512]);                           \
    gload_lds16(bS + ko,          &sB[S][stD]);                                 \
    gload_lds16(bS + ko + 16 * K, &sB[S][stD + 512]);                           \
  }
#define COMPUTE(S)                                                              \
  {                                                                             \
    bf16x8 af[4], bf[4];                                                        \
    _Pragma("unroll") for (int mi = 0; mi < 4; ++mi)                            \
      af[mi] = *(const bf16x8*)&sA[S][rdA + mi * 512];                          \
    _Pragma("unroll") for (int ni = 0; ni < 4; ++ni)                            \
      bf[ni] = *(const bf16x8*)&sB[S][rdB + ni * 512];                          \
    __builtin_amdgcn_s_setprio(1);                                              \
    _Pragma("unroll") for (int mi = 0; mi < 4; ++mi)                            \
      _Pragma("unroll") for (int ni = 0; ni < 4; ++ni)                          \
        acc[mi][ni] = __builtin_amdgcn_mfma_f32_16x16x32_bf16(af[mi], bf[ni],   \
                                                              acc[mi][ni], 0, 0, 0); \
    __builtin_amdgcn_s_setprio(0);                                              \
  }
#define WAITBAR4                                                                \
  asm volatile("s_waitcnt vmcnt(4)" ::: "memory");                              \
  __builtin_amdgcn_sched_barrier(0);                                            \
  __builtin_amdgcn_s_barrier();

  STAGE(0, 0);
  STAGE(1, 1);
  WAITBAR4;

  #pragma unroll 1
  for (int kt = 0; kt < 30; kt += 3) {
    STAGE(kt + 2, 2); COMPUTE(0); WAITBAR4;
    STAGE(kt + 3, 0); COMPUTE(1); WAITBAR4;
    STAGE(kt + 4, 1); COMPUTE(2); WAITBAR4;
  }
  COMPUTE(0);
  asm volatile("s_waitcnt vmcnt(0)" ::: "memory");
  __builtin_amdgcn_sched_barrier(0);
  __builtin_amdgcn_s_barrier();
  COMPUTE(1);
#undef STAGE
#undef COMPUTE
#undef WAITBAR4

  #pragma unroll
  for (int mt = 0; mt < 4; ++mt)
    #pragma unroll
    for (int nt = 0; nt < 4; ++nt)
      #pragma unroll
      for (int r = 0; r < 4; ++r) {
        const int rr = row0 + wm * 64 + mt * 16 + lhi * 4 + r;
        const int cc = col0 + wn * 64 + nt * 16 + l15;
        float v = acc[mt][nt][r];
        if (QSCALE && cc < CDIM) v *= 0.18033688011f;   // 0.125 * log2(e)
        if constexpr (sizeof(OT) == 2) C[(size_t)rr * N + cc] = f32_to_bf16(v);
        else                           C[(size_t)rr * N + cc] = v;
      }
}

// ---------------------------------------------------------------- flash attention
// Round-11: round-9 structure (pa = 4k+w pairing - round-10 interleave reverted,
// it regressed) + ROWSUM-VIA-ONES-MFMA: one extra mfma(pa, ONES, acc1) per
// job-step puts rowsum(q) in every lane's column -> removes the 8 v_add/step
// lsum chain AND the entire epilogue shuffle reduction (normalizer lands in
// the correct lane/reg directly, and matches the bf16-rounded P used for PV).
template <bool DOMASK>
__device__ __forceinline__ void attn_step(const bf16x8 (&qf)[2],
                                          const bf16x8 (&kf)[2][2],
                                          const bf16x8 (&vb)[4],
                                          const bf16x8 ones,
                                          f32x4 (&acc)[4], f32x4& acc1,
                                          int l15, int lhi, int kv0, int qg) {
  f32x4 st[2];
  #pragma unroll
  for (int t = 0; t < 2; ++t) {
    f32x4 z = {0.f, 0.f, 0.f, 0.f};
    z = __builtin_amdgcn_mfma_f32_16x16x32_bf16(kf[t][0], qf[0], z, 0, 0, 0);
    z = __builtin_amdgcn_mfma_f32_16x16x32_bf16(kf[t][1], qf[1], z, 0, 0, 0);
    st[t] = z;
  }
  #pragma unroll
  for (int t = 0; t < 2; ++t)
    #pragma unroll
    for (int r = 0; r < 4; ++r) {
      float sv = st[t][r];                       // Q pre-scaled: log2-domain score
      if (DOMASK) {
        const int kvg = kv0 + t * 16 + lhi * 4 + r;
        sv = (kvg > qg) ? -__builtin_inff() : sv;
      }
      st[t][r] = exp2f(sv);
    }
  // In-register P^T -> PA transpose among the 4 lane-groups sharing l15.
  unsigned c00, c01, c10, c11;
  asm("v_cvt_pk_bf16_f32 %0, %1, %2" : "=v"(c00) : "v"(st[0][0]), "v"(st[0][1]));
  asm("v_cvt_pk_bf16_f32 %0, %1, %2" : "=v"(c01) : "v"(st[0][2]), "v"(st[0][3]));
  asm("v_cvt_pk_bf16_f32 %0, %1, %2" : "=v"(c10) : "v"(st[1][0]), "v"(st[1][1]));
  asm("v_cvt_pk_bf16_f32 %0, %1, %2" : "=v"(c11) : "v"(st[1][2]), "v"(st[1][3]));
  asm("v_permlane32_swap_b32 %0, %1" : "+v"(c00), "+v"(c10));
  asm("v_permlane32_swap_b32 %0, %1" : "+v"(c01), "+v"(c11));
  asm("v_permlane16_swap_b32 %0, %1" : "+v"(c00), "+v"(c10));
  asm("v_permlane16_swap_b32 %0, %1" : "+v"(c01), "+v"(c11));
  uint32x4 pw; pw[0] = c00; pw[1] = c01; pw[2] = c10; pw[3] = c11;
  const bf16x8 pa = __builtin_bit_cast(bf16x8, pw);
  #pragma unroll
  for (int d = 0; d < 4; ++d)
    acc[d] = __builtin_amdgcn_mfma_f32_16x16x32_bf16(pa, vb[d], acc[d], 0, 0, 0);
  acc1 = __builtin_amdgcn_mfma_f32_16x16x32_bf16(pa, ones, acc1, 0, 0, 0);
}

__global__ __launch_bounds__(256, 4) void attn_kernel(const u16* __restrict__ QKV,
                                                      const u16* __restrict__ Kc,
                                                      const u16* __restrict__ Vc,
                                                      u16* __restrict__ Y) {
  __shared__ u16 Kl[2][2048];     // [buf][4 frags x 64 lanes x 8 u16] = 4KB each
  __shared__ u16 Vl[2][2048];
  const int tid = threadIdx.x, lane = tid & 63, wid = tid >> 6;
  const int l15 = lane & 15, lhi = lane >> 4;
  // XCD-aware decode: id = xcd + 8*k + 128*(bh>>3), xcd = bh&7.
  const int id = blockIdx.x;
  const int xcd = id & 7, k = (id >> 3) & 15, hi3 = id >> 7;
  const int bh = hi3 * 8 + xcd;
  const int b = bh >> 4, h = bh & 15;
  const int pa = k * 4 + wid;                    // pair index 0..63 (round-9 mapping)
  const int qA0 = pa * 16, qB0 = (127 - pa) * 16;
  const int nchA = pa / 2 + 1, nchB = (127 - pa) / 2 + 1;
  const int ncmax = (127 - k * 4) / 2 + 1;       // block-uniform chunk count (wid 0)
  const size_t base = (size_t)b * SEQ_T * QKVC;
  const u16* Qp  = QKV + base + h * 64;
  const u16* KcC = Kc + (size_t)bh * 131072;
  const u16* VcC = Vc + (size_t)bh * 131072;

  // ones fragment for the rowsum MFMA (bf16 1.0 = 0x3F80)
  u16x8 ou;
  #pragma unroll
  for (int j = 0; j < 8; ++j) ou[j] = 0x3F80;
  const bf16x8 ones = __builtin_bit_cast(bf16x8, ou);

  // stage chunk 0 (each wave: 1KB of K + 1KB of V)
  gload_lds16(KcC + wid * 512 + lane * 8, &Kl[0][wid * 512]);
  gload_lds16(VcC + wid * 512 + lane * 8, &Vl[0][wid * 512]);

  bf16x8 qfA[2], qfB[2];
  #pragma unroll
  for (int i = 0; i < 2; ++i) {
    qfA[i] = *(const bf16x8*)(Qp + (size_t)(qA0 + l15) * QKVC + i * 32 + lhi * 8);
    qfB[i] = *(const bf16x8*)(Qp + (size_t)(qB0 + l15) * QKVC + i * 32 + lhi * 8);
  }
  const int qgA = qA0 + l15, qgB = qB0 + l15;

  f32x4 accA[4] = {}, accB[4] = {};
  f32x4 acc1A = {}, acc1B = {};

  __syncthreads();

  int cbuf = 0;
  for (int ic = 0; ic < ncmax; ++ic) {
    // prefetch next chunk into the other buffer (block-uniform condition)
    if (ic + 1 < ncmax) {
      const u16* kg = KcC + (size_t)(ic + 1) * 2048 + wid * 512 + lane * 8;
      const u16* vg = VcC + (size_t)(ic + 1) * 2048 + wid * 512 + lane * 8;
      gload_lds16(kg, &Kl[cbuf ^ 1][wid * 512]);
      gload_lds16(vg, &Vl[cbuf ^ 1][wid * 512]);
    }
    // conflict-free lane-linear ds_read_b128 fragments (shared by both jobs)
    const u16* kb = &Kl[cbuf][0];
    const u16* vp = &Vl[cbuf][0];
    bf16x8 kf[2][2], vb[4];
    #pragma unroll
    for (int t = 0; t < 2; ++t)
      #pragma unroll
      for (int i = 0; i < 2; ++i)
        kf[t][i] = *(const bf16x8*)(kb + (t * 2 + i) * 512 + lane * 8);
    #pragma unroll
    for (int d = 0; d < 4; ++d)
      vb[d] = *(const bf16x8*)(vp + d * 512 + lane * 8);

    const int kv0 = ic * 32;
    if (ic < nchB) {
      if (ic == nchB - 1)
        attn_step<true>(qfB, kf, vb, ones, accB, acc1B, l15, lhi, kv0, qgB);
      else
        attn_step<false>(qfB, kf, vb, ones, accB, acc1B, l15, lhi, kv0, qgB);
    }
    if (ic < nchA) {
      if (ic == nchA - 1)
        attn_step<true>(qfA, kf, vb, ones, accA, acc1A, l15, lhi, kv0, qgA);
      else
        attn_step<false>(qfA, kf, vb, ones, accA, acc1A, l15, lhi, kv0, qgA);
    }
    __syncthreads();
    cbuf ^= 1;
  }

  // epilogue: rowsum already in the right lane/reg (acc1[r]) - no shuffles
  u16* Yp = Y + (size_t)b * SEQ_T * CDIM + h * 64;
  #pragma unroll
  for (int r = 0; r < 4; ++r) {
    const float ivA = 1.0f / acc1A[r];
    const float ivB = 1.0f / acc1B[r];
    #pragma unroll
    for (int d = 0; d < 4; ++d) {
      Yp[(size_t)(qA0 + lhi * 4 + r) * CDIM + d * 16 + l15] = f32_to_bf16(accA[d][r] * ivA);
      Yp[(size_t)(qB0 + lhi * 4 + r) * CDIM + d * 16 + l15] = f32_to_bf16(accB[d][r] * ivB);
    }
  }
}

// ---------------------------------------------------------------- launch
extern "C" void kernel_launch(void* const* d_in, const int* in_sizes, int n_in,
                              void* d_out, int out_size, void* d_ws, size_t ws_size,
                              hipStream_t stream) {
  const float* x      = (const float*)d_in[0];
  const float* w_qkv  = (const float*)d_in[1];
  const float* w_proj = (const float*)d_in[2];
  float* out = (float*)d_out;

  u16* Xb  = (u16*)d_ws;                                // 8192*1024 bf16 (dead after GEMM1)
  u16* Wqt = Xb  + (size_t)MROWS * CDIM;                // 3072*1024
  u16* Wpt = Wqt + (size_t)QKVC * CDIM;                 // 1024*1024
  u16* QKV = Wpt + (size_t)CDIM * CDIM;                 // 8192*3072
  u16* Yb  = QKV + (size_t)MROWS * QKVC;                // 8192*1024
  u16* Vc  = Yb  + (size_t)MROWS * CDIM;                // 64*131072 (blocked V)
  u16* Kc  = Xb;                                        // 64*131072 (blocked K, aliases Xb)

  // casts / transposes
  cast_bf16_kernel<<<(MROWS * CDIM / 4 + 255) / 256, 256, 0, stream>>>(x, Xb, MROWS * CDIM / 4);
  transpose_cast_kernel<<<dim3(QKVC / 32, CDIM / 32), dim3(32, 8), 0, stream>>>(w_qkv, Wqt, CDIM, QKVC);
  transpose_cast_kernel<<<dim3(CDIM / 32, CDIM / 32), dim3(32, 8), 0, stream>>>(w_proj, Wpt, CDIM, CDIM);

  // qkv = x @ w_qkv  (bf16 out; Q columns pre-scaled by 0.125*log2e)
  gemm_bt_kernel<u16, true><<<dim3(MROWS / 128, QKVC / 128), 256, 0, stream>>>(Xb, Wqt, QKV, QKVC, CDIM);

  // K/V repack into lane-linear fragment tiles (Kc overwrites Xb - safe after GEMM1)
  repack_k_kernel<<<dim3(SEQ_T / 32, NBATCH * NHEAD), 256, 0, stream>>>(QKV, Kc);
  repack_v_kernel<<<dim3(SEQ_T / 32, 2, NBATCH * NHEAD), dim3(32, 8), 0, stream>>>(QKV, Vc);

  // attention (round-9 pairing, rowsum-via-MFMA, XCD-clustered, LDS staging)
  attn_kernel<<<1024, 256, 0, stream>>>(QKV, Kc, Vc, Yb);

  // out = y @ w_proj  (f32 out)
  gemm_bt_kernel<float, false><<<dim3(MROWS / 128, CDIM / 128), 256, 0, stream>>>(Yb, Wpt, out, CDIM, CDIM);
}